// Round 1
// baseline (1177.855 us; speedup 1.0000x reference)
//
#include <hip/hip_runtime.h>
#include <hip/hip_bf16.h>
#include <cstddef>
#include <cstdint>

#define B_   4
#define N_   8192
#define C_   768
#define H_   4
#define D_   192
#define CQ_  2304   // 3*C
#define M_   32768  // B*N

typedef __attribute__((ext_vector_type(8))) short short8_t;
typedef __attribute__((ext_vector_type(4))) float f32x4;

__device__ inline ushort f2bf(float f){
  uint u = __float_as_uint(f);
  u += 0x7FFFu + ((u >> 16) & 1u);   // RNE; inputs are finite
  return (ushort)(u >> 16);
}
__device__ inline float bf2f(ushort u){ return __uint_as_float(((uint)u) << 16); }

// ---------------- fp32 -> bf16 conversion (vectorized) ----------------
__global__ __launch_bounds__(256) void cvt_bf16(const float* __restrict__ src,
                                                ushort* __restrict__ dst, int n4){
  int i = blockIdx.x * 256 + threadIdx.x;
  if (i < n4){
    float4 v = ((const float4*)src)[i];
    ushort4 o;
    o.x = f2bf(v.x); o.y = f2bf(v.y); o.z = f2bf(v.z); o.w = f2bf(v.w);
    ((ushort4*)dst)[i] = o;
  }
}

// ---------------- QKV projection: [32768,768] x [2304,768]^T -> bf16 [32768,2304]
__global__ __launch_bounds__(256) void gemm_qkvv(const ushort* __restrict__ A,
                                                 const ushort* __restrict__ W,
                                                 ushort* __restrict__ Cq){
  __shared__ __align__(16) ushort As[128][40];  // +8 pad: 2-way-max bank aliasing
  __shared__ __align__(16) ushort Bs[128][40];
  const int t = threadIdx.x;
  const int m0 = blockIdx.y * 128;
  const int n0 = blockIdx.x * 128;
  const int w  = t >> 6, lane = t & 63;
  const int wr = w >> 1, wc = w & 1;
  const int lr = lane & 15, lg = lane >> 4;

  f32x4 acc[4][4];
  #pragma unroll
  for (int i = 0; i < 4; ++i)
    #pragma unroll
    for (int j = 0; j < 4; ++j)
      acc[i][j] = (f32x4){0.f, 0.f, 0.f, 0.f};

  const int r0 = t >> 2,          c0 = (t & 3) * 8;
  const int r1 = (t + 256) >> 2,  c1 = (t & 3) * 8;

  for (int kt = 0; kt < 24; ++kt){
    const int k0 = kt * 32;
    __syncthreads();
    {
      int4 va0 = *(const int4*)(A + (size_t)(m0 + r0) * 768 + k0 + c0);
      int4 va1 = *(const int4*)(A + (size_t)(m0 + r1) * 768 + k0 + c1);
      int4 vb0 = *(const int4*)(W + (size_t)(n0 + r0) * 768 + k0 + c0);
      int4 vb1 = *(const int4*)(W + (size_t)(n0 + r1) * 768 + k0 + c1);
      *(int4*)(&As[r0][c0]) = va0;
      *(int4*)(&As[r1][c1]) = va1;
      *(int4*)(&Bs[r0][c0]) = vb0;
      *(int4*)(&Bs[r1][c1]) = vb1;
    }
    __syncthreads();
    short8_t af[4], bf[4];
    #pragma unroll
    for (int f = 0; f < 4; ++f)
      af[f] = *(const short8_t*)(&As[wr*64 + f*16 + lr][lg*8]);
    #pragma unroll
    for (int f = 0; f < 4; ++f)
      bf[f] = *(const short8_t*)(&Bs[wc*64 + f*16 + lr][lg*8]);
    #pragma unroll
    for (int i = 0; i < 4; ++i)
      #pragma unroll
      for (int j = 0; j < 4; ++j)
        acc[i][j] = __builtin_amdgcn_mfma_f32_16x16x32_bf16(af[i], bf[j], acc[i][j], 0, 0, 0);
  }
  #pragma unroll
  for (int i = 0; i < 4; ++i)
    #pragma unroll
    for (int j = 0; j < 4; ++j)
      #pragma unroll
      for (int r = 0; r < 4; ++r){
        int m = m0 + wr*64 + i*16 + lg*4 + r;
        int c = n0 + wc*64 + j*16 + lr;
        Cq[(size_t)m * CQ_ + c] = f2bf(acc[i][j][r]);
      }
}

// ---------------- column sum-of-squares over N for q,k (cols 0..1535) -------
__global__ __launch_bounds__(256) void colsq(const ushort* __restrict__ Q,
                                             float* __restrict__ norm2){
  const int c  = blockIdx.x * 256 + threadIdx.x;  // [0,1536)
  const int b  = blockIdx.y;
  const int n0 = blockIdx.z * 512;
  const ushort* p = Q + (size_t)(b * N_ + n0) * CQ_ + c;
  float acc = 0.f;
  for (int i = 0; i < 512; ++i){
    float v = bf2f(*p);
    acc = fmaf(v, v, acc);
    p += CQ_;
  }
  atomicAdd(&norm2[b * 1536 + c], acc);
}

// ---------------- Gram: S[bh][d][e] = sum_n q[n][d] * k[n][e] ---------------
__global__ __launch_bounds__(256) void gram(const ushort* __restrict__ Q,
                                            float* __restrict__ S){
  const int bh = blockIdx.y;            // 16
  const int b = bh >> 2, h = bh & 3;
  const int nbase = blockIdx.x * 256;   // 32 chunks
  __shared__ __align__(16) ushort qs[8][200];
  __shared__ __align__(16) ushort ks[8][200];
  const int t  = threadIdx.x;
  const int tx = t & 15, ty = t >> 4;
  float a[12][12];
  #pragma unroll
  for (int i = 0; i < 12; ++i)
    #pragma unroll
    for (int j = 0; j < 12; ++j) a[i][j] = 0.f;

  for (int it = 0; it < 32; ++it){
    __syncthreads();
    #pragma unroll
    for (int li = 0; li < 6; ++li){
      int i = li * 256 + t;                    // [0,1536)
      int mat = (i >= 768) ? 1 : 0;
      int j = i - mat * 768;
      int row = j / 96;
      int c2  = j - row * 96;
      const uint* src = (const uint*)(Q + (size_t)(b*N_ + nbase + it*8 + row) * CQ_
                                        + mat * 768 + h * 192);
      uint v = src[c2];
      uint* dstrow = (uint*)(mat ? ks[row] : qs[row]);
      dstrow[c2] = v;
    }
    __syncthreads();
    #pragma unroll
    for (int r = 0; r < 8; ++r){
      float qv[12], kv[12];
      const uint* qrow = (const uint*)qs[r];
      const uint* krow = (const uint*)ks[r];
      #pragma unroll
      for (int u = 0; u < 6; ++u){
        uint wq = qrow[tx*6 + u];
        qv[2*u]   = __uint_as_float(wq << 16);
        qv[2*u+1] = __uint_as_float(wq & 0xFFFF0000u);
        uint wk = krow[ty*6 + u];
        kv[2*u]   = __uint_as_float(wk << 16);
        kv[2*u+1] = __uint_as_float(wk & 0xFFFF0000u);
      }
      #pragma unroll
      for (int i = 0; i < 12; ++i)
        #pragma unroll
        for (int j = 0; j < 12; ++j)
          a[i][j] = fmaf(qv[i], kv[j], a[i][j]);
    }
  }
  float* Sp = S + (size_t)bh * 192 * 192;
  #pragma unroll
  for (int i = 0; i < 12; ++i)
    #pragma unroll
    for (int j = 0; j < 12; ++j)
      atomicAdd(&Sp[(tx*12 + i) * 192 + (ty*12 + j)], a[i][j]);
}

// ---------------- softmax rows with temperature + l2-norm folding ----------
__global__ __launch_bounds__(256) void softmax_k(const float* __restrict__ S,
                                                 const float* __restrict__ norm2,
                                                 const float* __restrict__ temp,
                                                 ushort* __restrict__ attn){
  const int wid  = blockIdx.x * 4 + (threadIdx.x >> 6);  // row id [0,3072)
  const int lane = threadIdx.x & 63;
  const int bh = wid / 192, d = wid % 192;
  const int b = bh >> 2, h = bh & 3;
  const float nq = sqrtf(norm2[b*1536 + h*192 + d]);
  const float sc = temp[h] / fmaxf(nq, 1e-12f);
  const float* Sr = S + ((size_t)bh * 192 + d) * 192;
  float l[3];
  #pragma unroll
  for (int u = 0; u < 3; ++u){
    int e = lane + u * 64;
    float nk = sqrtf(norm2[b*1536 + 768 + h*192 + e]);
    l[u] = Sr[e] * sc / fmaxf(nk, 1e-12f);
  }
  float m = fmaxf(l[0], fmaxf(l[1], l[2]));
  #pragma unroll
  for (int off = 32; off; off >>= 1) m = fmaxf(m, __shfl_xor(m, off));
  float p[3], s = 0.f;
  #pragma unroll
  for (int u = 0; u < 3; ++u){ p[u] = expf(l[u] - m); s += p[u]; }
  #pragma unroll
  for (int off = 32; off; off >>= 1) s += __shfl_xor(s, off);
  float inv = 1.f / s;
  ushort* ar = attn + ((size_t)bh * 192 + d) * 192;
  #pragma unroll
  for (int u = 0; u < 3; ++u) ar[lane + u*64] = f2bf(p[u] * inv);
}

// ---------------- out[n][h*192+d] = sum_e V[n][e] * attn[d][e] --------------
__global__ __launch_bounds__(256) void out_gemm(const ushort* __restrict__ Q,
                                                const ushort* __restrict__ attn,
                                                float* __restrict__ out){
  const int bh = blockIdx.y;
  const int b = bh >> 2, h = bh & 3;
  const int n0 = blockIdx.x * 128;
  const int t = threadIdx.x, w = t >> 6, lane = t & 63;
  const int wn = w & 1, wd = w >> 1;
  const int lr = lane & 15, lg = lane >> 4;
  f32x4 acc[4][6];
  #pragma unroll
  for (int i = 0; i < 4; ++i)
    #pragma unroll
    for (int j = 0; j < 6; ++j)
      acc[i][j] = (f32x4){0.f, 0.f, 0.f, 0.f};

  const ushort* Vbase = Q + 1536 + h * 192;            // + row*CQ_
  const ushort* Abase = attn + (size_t)bh * 192 * 192; // [d][e]

  #pragma unroll
  for (int kk = 0; kk < 6; ++kk){
    const int e = kk * 32 + lg * 8;
    short8_t av[4], bv[6];
    #pragma unroll
    for (int f = 0; f < 4; ++f){
      int n = n0 + wn*64 + f*16 + lr;
      av[f] = *(const short8_t*)(Vbase + (size_t)(b*N_ + n) * CQ_ + e);
    }
    #pragma unroll
    for (int f = 0; f < 6; ++f){
      int d = wd*96 + f*16 + lr;
      bv[f] = *(const short8_t*)(Abase + d * 192 + e);
    }
    #pragma unroll
    for (int i = 0; i < 4; ++i)
      #pragma unroll
      for (int j = 0; j < 6; ++j)
        acc[i][j] = __builtin_amdgcn_mfma_f32_16x16x32_bf16(av[i], bv[j], acc[i][j], 0, 0, 0);
  }
  #pragma unroll
  for (int i = 0; i < 4; ++i)
    #pragma unroll
    for (int j = 0; j < 6; ++j)
      #pragma unroll
      for (int r = 0; r < 4; ++r){
        int n = n0 + wn*64 + i*16 + lg*4 + r;
        int c = h*192 + wd*96 + j*16 + lr;
        out[(size_t)(b*N_ + n) * 768 + c] = acc[i][j][r];
      }
}

// ---------------------------------------------------------------------------
extern "C" void kernel_launch(void* const* d_in, const int* in_sizes, int n_in,
                              void* d_out, int out_size, void* d_ws, size_t ws_size,
                              hipStream_t stream){
  const float* x    = (const float*)d_in[0];
  const float* Wq   = (const float*)d_in[1];
  const float* temp = (const float*)d_in[2];
  float* out = (float*)d_out;
  char* ws = (char*)d_ws;

  // workspace layout (bytes)
  ushort* xb    = (ushort*)(ws + 0);          //  50,331,648
  ushort* Wb    = (ushort*)(ws + 50331648);   //   3,538,944
  ushort* qkvv  = (ushort*)(ws + 53870592);   // 150,994,944
  float*  norm2 = (float*)(ws + 204865536);   //      24,576
  float*  S     = (float*)(ws + 204890112);   //   2,359,296
  ushort* attn  = (ushort*)(ws + 207249408);  //   1,179,648

  // zero atomic accumulation targets (norm2 + S are contiguous)
  hipMemsetAsync(norm2, 0, 24576 + 2359296, stream);

  cvt_bf16<<<6291456/256, 256, 0, stream>>>(x,  xb, 6291456);   // 25.2M floats /4
  cvt_bf16<<<442368/256,  256, 0, stream>>>(Wq, Wb, 442368);    // 1.77M floats /4

  gemm_qkvv<<<dim3(18, 256), 256, 0, stream>>>(xb, Wb, qkvv);

  colsq<<<dim3(6, 4, 16), 256, 0, stream>>>(qkvv, norm2);
  gram<<<dim3(32, 16), 256, 0, stream>>>(qkvv, S);
  softmax_k<<<768, 256, 0, stream>>>(S, norm2, temp, attn);
  out_gemm<<<dim3(64, 16), 256, 0, stream>>>(qkvv, attn, out);
}

// Round 2
// 318.098 us; speedup vs baseline: 3.7028x; 3.7028x over previous
//
#include <hip/hip_runtime.h>
#include <hip/hip_bf16.h>
#include <cstddef>
#include <cstdint>

#define B_   4
#define N_   8192
#define C_   768
#define H_   4
#define D_   192
#define CQ_  2304   // 3*C
#define M_   32768  // B*N

typedef __attribute__((ext_vector_type(8))) short short8_t;
typedef __attribute__((ext_vector_type(4))) float f32x4;

__device__ inline ushort f2bf(float f){
  uint u = __float_as_uint(f);
  u += 0x7FFFu + ((u >> 16) & 1u);   // RNE; inputs are finite
  return (ushort)(u >> 16);
}
__device__ inline float bf2f(ushort u){ return __uint_as_float(((uint)u) << 16); }

// ---------------- fp32 -> bf16 conversion (vectorized) ----------------
__global__ __launch_bounds__(256) void cvt_bf16(const float* __restrict__ src,
                                                ushort* __restrict__ dst, int n4){
  int i = blockIdx.x * 256 + threadIdx.x;
  if (i < n4){
    float4 v = ((const float4*)src)[i];
    ushort4 o;
    o.x = f2bf(v.x); o.y = f2bf(v.y); o.z = f2bf(v.z); o.w = f2bf(v.w);
    ((ushort4*)dst)[i] = o;
  }
}

// ---------------- QKV projection: [32768,768] x [2304,768]^T -> bf16 [32768,2304]
__global__ __launch_bounds__(256) void gemm_qkvv(const ushort* __restrict__ A,
                                                 const ushort* __restrict__ W,
                                                 ushort* __restrict__ Cq){
  __shared__ __align__(16) ushort As[128][40];
  __shared__ __align__(16) ushort Bs[128][40];
  const int t = threadIdx.x;
  const int m0 = blockIdx.y * 128;
  const int n0 = blockIdx.x * 128;
  const int w  = t >> 6, lane = t & 63;
  const int wr = w >> 1, wc = w & 1;
  const int lr = lane & 15, lg = lane >> 4;

  f32x4 acc[4][4];
  #pragma unroll
  for (int i = 0; i < 4; ++i)
    #pragma unroll
    for (int j = 0; j < 4; ++j)
      acc[i][j] = (f32x4){0.f, 0.f, 0.f, 0.f};

  const int r0 = t >> 2,          c0 = (t & 3) * 8;
  const int r1 = (t + 256) >> 2,  c1 = (t & 3) * 8;

  for (int kt = 0; kt < 24; ++kt){
    const int k0 = kt * 32;
    __syncthreads();
    {
      int4 va0 = *(const int4*)(A + (size_t)(m0 + r0) * 768 + k0 + c0);
      int4 va1 = *(const int4*)(A + (size_t)(m0 + r1) * 768 + k0 + c1);
      int4 vb0 = *(const int4*)(W + (size_t)(n0 + r0) * 768 + k0 + c0);
      int4 vb1 = *(const int4*)(W + (size_t)(n0 + r1) * 768 + k0 + c1);
      *(int4*)(&As[r0][c0]) = va0;
      *(int4*)(&As[r1][c1]) = va1;
      *(int4*)(&Bs[r0][c0]) = vb0;
      *(int4*)(&Bs[r1][c1]) = vb1;
    }
    __syncthreads();
    short8_t af[4], bf[4];
    #pragma unroll
    for (int f = 0; f < 4; ++f)
      af[f] = *(const short8_t*)(&As[wr*64 + f*16 + lr][lg*8]);
    #pragma unroll
    for (int f = 0; f < 4; ++f)
      bf[f] = *(const short8_t*)(&Bs[wc*64 + f*16 + lr][lg*8]);
    #pragma unroll
    for (int i = 0; i < 4; ++i)
      #pragma unroll
      for (int j = 0; j < 4; ++j)
        acc[i][j] = __builtin_amdgcn_mfma_f32_16x16x32_bf16(af[i], bf[j], acc[i][j], 0, 0, 0);
  }
  #pragma unroll
  for (int i = 0; i < 4; ++i)
    #pragma unroll
    for (int j = 0; j < 4; ++j)
      #pragma unroll
      for (int r = 0; r < 4; ++r){
        int m = m0 + wr*64 + i*16 + lg*4 + r;
        int c = n0 + wc*64 + j*16 + lr;
        Cq[(size_t)m * CQ_ + c] = f2bf(acc[i][j][r]);
      }
}

// ---------------- column sum-of-squares over N for q,k (cols 0..1535) -------
__global__ __launch_bounds__(256) void colsq(const ushort* __restrict__ Q,
                                             float* __restrict__ norm2){
  const int c  = blockIdx.x * 256 + threadIdx.x;  // [0,1536)
  const int b  = blockIdx.y;
  const int n0 = blockIdx.z * 512;
  const ushort* p = Q + (size_t)(b * N_ + n0) * CQ_ + c;
  float acc = 0.f;
  for (int i = 0; i < 512; ++i){
    float v = bf2f(*p);
    acc = fmaf(v, v, acc);
    p += CQ_;
  }
  atomicAdd(&norm2[b * 1536 + c], acc);
}

// ---------------- Gram via MFMA: S_part[kc][bh][d][e] partial sums ----------
// S[d][e] = sum_n q[n][d]*k[n][e].  Stage [32 n][d] tiles in LDS (natural
// layout, coalesced), gather transposed fragments via conflict-free u16 reads.
__global__ __launch_bounds__(256) void gram_mfma(const ushort* __restrict__ Qk,
                                                 float* __restrict__ Sp){
  const int kc = blockIdx.x;      // 16 K-chunks of 512 rows
  const int bh = blockIdx.y;      // 16
  const int eh = blockIdx.z;      // 2 e-halves of 96
  const int b = bh >> 2, h = bh & 3;
  __shared__ __align__(16) ushort qs[32][194];   // pad 194: 97 = 1 mod 32
  __shared__ __align__(16) ushort ks[32][98];    // pad  98: 49 = 17 mod 32
  const int t = threadIdx.x;
  const int w = t >> 6, lane = t & 63;
  const int wd = w >> 1, we = w & 1;             // wave: d-half x e-quarter
  const int lr = lane & 15, lg = lane >> 4;

  f32x4 acc[6][3];
  #pragma unroll
  for (int i = 0; i < 6; ++i)
    #pragma unroll
    for (int j = 0; j < 3; ++j)
      acc[i][j] = (f32x4){0.f, 0.f, 0.f, 0.f};

  const uint* qb = (const uint*)Qk + ((size_t)b * N_ * CQ_ + h * 192) / 2;
  const uint* kb = (const uint*)Qk + ((size_t)b * N_ * CQ_ + 768 + h * 192 + eh * 96) / 2;

  for (int it = 0; it < 16; ++it){
    const int n0 = kc * 512 + it * 32;
    __syncthreads();
    // q tile: 32 rows x 96 uints = 768 uint4
    #pragma unroll
    for (int u = 0; u < 3; ++u){
      int g = u * 256 + t;
      int row = g / 24, c4 = g % 24;
      uint4 v = ((const uint4*)(qb + (size_t)(n0 + row) * 1152))[c4];
      uint* dst = (uint*)&qs[row][8 * c4];
      dst[0] = v.x; dst[1] = v.y; dst[2] = v.z; dst[3] = v.w;
    }
    // k tile: 32 rows x 48 uints = 768 uint2
    #pragma unroll
    for (int u = 0; u < 3; ++u){
      int g = u * 256 + t;
      int row = g / 24, c2 = g % 24;
      uint2 v = ((const uint2*)(kb + (size_t)(n0 + row) * 1152))[c2];
      uint* dst = (uint*)&ks[row][4 * c2];
      dst[0] = v.x; dst[1] = v.y;
    }
    __syncthreads();
    // fragments: A[d][n] gathered from qs[n][d] (u16, 2 lanes/bank = free)
    union { uint u[4]; short8_t v; } af[6], bf[3];
    #pragma unroll
    for (int i = 0; i < 6; ++i){
      int d = wd * 96 + i * 16 + lr;
      #pragma unroll
      for (int p = 0; p < 4; ++p)
        af[i].u[p] = (uint)qs[lg*8 + 2*p][d] | ((uint)qs[lg*8 + 2*p + 1][d] << 16);
    }
    #pragma unroll
    for (int j = 0; j < 3; ++j){
      int e = we * 48 + j * 16 + lr;
      #pragma unroll
      for (int p = 0; p < 4; ++p)
        bf[j].u[p] = (uint)ks[lg*8 + 2*p][e] | ((uint)ks[lg*8 + 2*p + 1][e] << 16);
    }
    #pragma unroll
    for (int i = 0; i < 6; ++i)
      #pragma unroll
      for (int j = 0; j < 3; ++j)
        acc[i][j] = __builtin_amdgcn_mfma_f32_16x16x32_bf16(af[i].v, bf[j].v, acc[i][j], 0, 0, 0);
  }
  float* base = Sp + (size_t)(kc * 16 + bh) * 192 * 192;
  #pragma unroll
  for (int i = 0; i < 6; ++i)
    #pragma unroll
    for (int j = 0; j < 3; ++j)
      #pragma unroll
      for (int r = 0; r < 4; ++r){
        int d = wd * 96 + i * 16 + lg * 4 + r;
        int e = eh * 96 + we * 48 + j * 16 + lr;
        base[(size_t)d * 192 + e] = acc[i][j][r];
      }
}

// ---------------- softmax rows: reduce 16 partial slices + temp + l2 fold ---
__global__ __launch_bounds__(256) void softmax_k(const float* __restrict__ Sp,
                                                 const float* __restrict__ norm2,
                                                 const float* __restrict__ temp,
                                                 ushort* __restrict__ attn){
  const int wid  = blockIdx.x * 4 + (threadIdx.x >> 6);  // row id [0,3072)
  const int lane = threadIdx.x & 63;
  const int bh = wid / 192, d = wid % 192;
  const int b = bh >> 2, h = bh & 3;
  const float nq = sqrtf(norm2[b*1536 + h*192 + d]);
  const float sc = temp[h] / fmaxf(nq, 1e-12f);
  const float* Sr = Sp + ((size_t)bh * 192 + d) * 192;
  float l[3];
  #pragma unroll
  for (int u = 0; u < 3; ++u){
    int e = lane + u * 64;
    float s = 0.f;
    #pragma unroll
    for (int kc = 0; kc < 16; ++kc)
      s += Sr[(size_t)kc * (16*192*192) + e];
    float nk = sqrtf(norm2[b*1536 + 768 + h*192 + e]);
    l[u] = s * sc / fmaxf(nk, 1e-12f);
  }
  float m = fmaxf(l[0], fmaxf(l[1], l[2]));
  #pragma unroll
  for (int off = 32; off; off >>= 1) m = fmaxf(m, __shfl_xor(m, off));
  float p[3], s = 0.f;
  #pragma unroll
  for (int u = 0; u < 3; ++u){ p[u] = expf(l[u] - m); s += p[u]; }
  #pragma unroll
  for (int off = 32; off; off >>= 1) s += __shfl_xor(s, off);
  float inv = 1.f / s;
  ushort* ar = attn + ((size_t)bh * 192 + d) * 192;
  #pragma unroll
  for (int u = 0; u < 3; ++u) ar[lane + u*64] = f2bf(p[u] * inv);
}

// ---------------- out[n][h*192+d] = sum_e V[n][e] * attn[d][e] --------------
__global__ __launch_bounds__(256) void out_gemm(const ushort* __restrict__ Q,
                                                const ushort* __restrict__ attn,
                                                float* __restrict__ out){
  const int bh = blockIdx.y;
  const int b = bh >> 2, h = bh & 3;
  const int n0 = blockIdx.x * 128;
  const int t = threadIdx.x, w = t >> 6, lane = t & 63;
  const int wn = w & 1, wd = w >> 1;
  const int lr = lane & 15, lg = lane >> 4;
  f32x4 acc[4][6];
  #pragma unroll
  for (int i = 0; i < 4; ++i)
    #pragma unroll
    for (int j = 0; j < 6; ++j)
      acc[i][j] = (f32x4){0.f, 0.f, 0.f, 0.f};

  const ushort* Vbase = Q + 1536 + h * 192;            // + row*CQ_
  const ushort* Abase = attn + (size_t)bh * 192 * 192; // [d][e]

  #pragma unroll
  for (int kk = 0; kk < 6; ++kk){
    const int e = kk * 32 + lg * 8;
    short8_t av[4], bv[6];
    #pragma unroll
    for (int f = 0; f < 4; ++f){
      int n = n0 + wn*64 + f*16 + lr;
      av[f] = *(const short8_t*)(Vbase + (size_t)(b*N_ + n) * CQ_ + e);
    }
    #pragma unroll
    for (int f = 0; f < 6; ++f){
      int d = wd*96 + f*16 + lr;
      bv[f] = *(const short8_t*)(Abase + d * 192 + e);
    }
    #pragma unroll
    for (int i = 0; i < 4; ++i)
      #pragma unroll
      for (int j = 0; j < 6; ++j)
        acc[i][j] = __builtin_amdgcn_mfma_f32_16x16x32_bf16(av[i], bv[j], acc[i][j], 0, 0, 0);
  }
  #pragma unroll
  for (int i = 0; i < 4; ++i)
    #pragma unroll
    for (int j = 0; j < 6; ++j)
      #pragma unroll
      for (int r = 0; r < 4; ++r){
        int n = n0 + wn*64 + i*16 + lg*4 + r;
        int c = h*192 + wd*96 + j*16 + lr;
        out[(size_t)(b*N_ + n) * 768 + c] = acc[i][j][r];
      }
}

// ---------------------------------------------------------------------------
extern "C" void kernel_launch(void* const* d_in, const int* in_sizes, int n_in,
                              void* d_out, int out_size, void* d_ws, size_t ws_size,
                              hipStream_t stream){
  const float* x    = (const float*)d_in[0];
  const float* Wq   = (const float*)d_in[1];
  const float* temp = (const float*)d_in[2];
  float* out = (float*)d_out;
  char* ws = (char*)d_ws;

  // workspace layout (bytes) — S_part/attn overlay xb (dead after gemm_qkvv)
  ushort* xb    = (ushort*)(ws + 0);          //  50,331,648 (dead after gemm)
  float*  S_part= (float*)(ws + 0);           //  37,748,736 (16 slices)
  ushort* attn  = (ushort*)(ws + 37748736);   //   1,179,648
  ushort* Wb    = (ushort*)(ws + 50331648);   //   3,538,944
  ushort* qkvv  = (ushort*)(ws + 53870592);   // 150,994,944
  float*  norm2 = (float*)(ws + 204865536);   //      24,576

  hipMemsetAsync(norm2, 0, 24576, stream);

  cvt_bf16<<<6291456/256, 256, 0, stream>>>(x,  xb, 6291456);
  cvt_bf16<<<442368/256,  256, 0, stream>>>(Wq, Wb, 442368);

  gemm_qkvv<<<dim3(18, 256), 256, 0, stream>>>(xb, Wb, qkvv);

  colsq<<<dim3(6, 4, 16), 256, 0, stream>>>(qkvv, norm2);
  gram_mfma<<<dim3(16, 16, 2), 256, 0, stream>>>(qkvv, S_part);
  softmax_k<<<768, 256, 0, stream>>>(S_part, norm2, temp, attn);
  out_gemm<<<dim3(64, 16), 256, 0, stream>>>(qkvv, attn, out);
}

// Round 3
// 287.319 us; speedup vs baseline: 4.0995x; 1.1071x over previous
//
#include <hip/hip_runtime.h>
#include <hip/hip_bf16.h>
#include <cstddef>
#include <cstdint>

#define B_   4
#define N_   8192
#define C_   768
#define H_   4
#define D_   192
#define CQ_  2304   // 3*C
#define M_   32768  // B*N

typedef __attribute__((ext_vector_type(8))) short short8_t;
typedef __attribute__((ext_vector_type(4))) float f32x4;

typedef const __attribute__((address_space(1))) uint gq_uint;
typedef __attribute__((address_space(3))) uint lds_uint;

__device__ inline ushort f2bf(float f){
  uint u = __float_as_uint(f);
  u += 0x7FFFu + ((u >> 16) & 1u);   // RNE; inputs are finite
  return (ushort)(u >> 16);
}
__device__ inline float bf2f(ushort u){ return __uint_as_float(((uint)u) << 16); }

// ---------------- fp32 -> bf16 conversion (vectorized) ----------------
__global__ __launch_bounds__(256) void cvt_bf16(const float* __restrict__ src,
                                                ushort* __restrict__ dst, int n4){
  int i = blockIdx.x * 256 + threadIdx.x;
  if (i < n4){
    float4 v = ((const float4*)src)[i];
    ushort4 o;
    o.x = f2bf(v.x); o.y = f2bf(v.y); o.z = f2bf(v.z); o.w = f2bf(v.w);
    ((ushort4*)dst)[i] = o;
  }
}

// ---------------- QKV projection: [32768,768] x [2304,768]^T -> bf16 [32768,2304]
// m97 structure: global_load_lds width=16, linear LDS [128][32], 2 barriers/K-step.
// Fused: column sum-of-squares for q,k (n0 < 1536) from fp32 accumulators.
__global__ __launch_bounds__(256) void gemm_qkvv(const ushort* __restrict__ A,
                                                 const ushort* __restrict__ W,
                                                 ushort* __restrict__ Cq,
                                                 float* __restrict__ norm2){
  __shared__ __align__(16) ushort As[128 * 32];
  __shared__ __align__(16) ushort Bs[128 * 32];
  const int t = threadIdx.x;
  const int m0 = blockIdx.y * 128;
  const int n0 = blockIdx.x * 128;
  const int w  = t >> 6, lane = t & 63;
  const int wr = w >> 1, wc = w & 1;
  const int lr = lane & 15, lg = lane >> 4;

  f32x4 acc[4][4];
  #pragma unroll
  for (int i = 0; i < 4; ++i)
    #pragma unroll
    for (int j = 0; j < 4; ++j)
      acc[i][j] = (f32x4){0.f, 0.f, 0.f, 0.f};

  // staging: chunk c = w*2+i covers LDS bytes [c*1024, c*1024+1024) which is
  // rows [c*16, c*16+16) x 64B; lane supplies row c*16+(lane>>2), colb (lane&3)*16
  const int srow = lane >> 2;
  const int scol = (lane & 3) * 8;   // ushort offset

  for (int kt = 0; kt < 24; ++kt){
    const int k0 = kt * 32;
    __syncthreads();
    #pragma unroll
    for (int i = 0; i < 2; ++i){
      const int c = w * 2 + i;
      const int row = c * 16 + srow;
      __builtin_amdgcn_global_load_lds(
          (gq_uint*)(const void*)(A + (size_t)(m0 + row) * 768 + k0 + scol),
          (lds_uint*)(void*)&As[c * 512], 16, 0, 0);
      __builtin_amdgcn_global_load_lds(
          (gq_uint*)(const void*)(W + (size_t)(n0 + row) * 768 + k0 + scol),
          (lds_uint*)(void*)&Bs[c * 512], 16, 0, 0);
    }
    __syncthreads();   // compiler emits vmcnt(0) drain here
    short8_t af[4], bf[4];
    #pragma unroll
    for (int f = 0; f < 4; ++f)
      af[f] = *(const short8_t*)(&As[(wr*64 + f*16 + lr) * 32 + lg*8]);
    #pragma unroll
    for (int f = 0; f < 4; ++f)
      bf[f] = *(const short8_t*)(&Bs[(wc*64 + f*16 + lr) * 32 + lg*8]);
    #pragma unroll
    for (int i = 0; i < 4; ++i)
      #pragma unroll
      for (int j = 0; j < 4; ++j)
        acc[i][j] = __builtin_amdgcn_mfma_f32_16x16x32_bf16(af[i], bf[j], acc[i][j], 0, 0, 0);
  }

  #pragma unroll
  for (int i = 0; i < 4; ++i)
    #pragma unroll
    for (int j = 0; j < 4; ++j)
      #pragma unroll
      for (int r = 0; r < 4; ++r){
        int m = m0 + wr*64 + i*16 + lg*4 + r;
        int c = n0 + wc*64 + j*16 + lr;
        Cq[(size_t)m * CQ_ + c] = f2bf(acc[i][j][r]);
      }

  // fused column sum-of-squares for q,k columns (n0 < 1536)
  if (n0 < 1536){
    const int b = m0 >> 13;   // m0 / 8192
    #pragma unroll
    for (int j = 0; j < 4; ++j){
      float s = 0.f;
      #pragma unroll
      for (int i = 0; i < 4; ++i)
        #pragma unroll
        for (int r = 0; r < 4; ++r)
          s = fmaf(acc[i][j][r], acc[i][j][r], s);
      // lanes lr, lr+16, lr+32, lr+48 hold the same column; tree-reduce
      s += __shfl_xor(s, 16);
      s += __shfl_xor(s, 32);
      if (lg == 0)
        atomicAdd(&norm2[b * 1536 + n0 + wc*64 + j*16 + lr], s);
    }
  }
}

// ---------------- Gram via MFMA: S_part[kc][bh][d][e] partial sums ----------
__global__ __launch_bounds__(256) void gram_mfma(const ushort* __restrict__ Qk,
                                                 float* __restrict__ Sp){
  const int kc = blockIdx.x;      // 16 K-chunks of 512 rows
  const int bh = blockIdx.y;      // 16
  const int eh = blockIdx.z;      // 2 e-halves of 96
  const int b = bh >> 2, h = bh & 3;
  __shared__ __align__(16) ushort qs[32][194];
  __shared__ __align__(16) ushort ks[32][98];
  const int t = threadIdx.x;
  const int w = t >> 6, lane = t & 63;
  const int wd = w >> 1, we = w & 1;
  const int lr = lane & 15, lg = lane >> 4;

  f32x4 acc[6][3];
  #pragma unroll
  for (int i = 0; i < 6; ++i)
    #pragma unroll
    for (int j = 0; j < 3; ++j)
      acc[i][j] = (f32x4){0.f, 0.f, 0.f, 0.f};

  const uint* qb = (const uint*)Qk + ((size_t)b * N_ * CQ_ + h * 192) / 2;
  const uint* kb = (const uint*)Qk + ((size_t)b * N_ * CQ_ + 768 + h * 192 + eh * 96) / 2;

  for (int it = 0; it < 16; ++it){
    const int n0 = kc * 512 + it * 32;
    __syncthreads();
    #pragma unroll
    for (int u = 0; u < 3; ++u){
      int g = u * 256 + t;
      int row = g / 24, c4 = g % 24;
      uint4 v = ((const uint4*)(qb + (size_t)(n0 + row) * 1152))[c4];
      uint* dst = (uint*)&qs[row][8 * c4];
      dst[0] = v.x; dst[1] = v.y; dst[2] = v.z; dst[3] = v.w;
    }
    #pragma unroll
    for (int u = 0; u < 3; ++u){
      int g = u * 256 + t;
      int row = g / 24, c2 = g % 24;
      uint2 v = ((const uint2*)(kb + (size_t)(n0 + row) * 1152))[c2];
      uint* dst = (uint*)&ks[row][4 * c2];
      dst[0] = v.x; dst[1] = v.y;
    }
    __syncthreads();
    union { uint u[4]; short8_t v; } af[6], bf[3];
    #pragma unroll
    for (int i = 0; i < 6; ++i){
      int d = wd * 96 + i * 16 + lr;
      #pragma unroll
      for (int p = 0; p < 4; ++p)
        af[i].u[p] = (uint)qs[lg*8 + 2*p][d] | ((uint)qs[lg*8 + 2*p + 1][d] << 16);
    }
    #pragma unroll
    for (int j = 0; j < 3; ++j){
      int e = we * 48 + j * 16 + lr;
      #pragma unroll
      for (int p = 0; p < 4; ++p)
        bf[j].u[p] = (uint)ks[lg*8 + 2*p][e] | ((uint)ks[lg*8 + 2*p + 1][e] << 16);
    }
    #pragma unroll
    for (int i = 0; i < 6; ++i)
      #pragma unroll
      for (int j = 0; j < 3; ++j)
        acc[i][j] = __builtin_amdgcn_mfma_f32_16x16x32_bf16(af[i].v, bf[j].v, acc[i][j], 0, 0, 0);
  }
  float* base = Sp + (size_t)(kc * 16 + bh) * 192 * 192;
  #pragma unroll
  for (int i = 0; i < 6; ++i)
    #pragma unroll
    for (int j = 0; j < 3; ++j)
      #pragma unroll
      for (int r = 0; r < 4; ++r){
        int d = wd * 96 + i * 16 + lg * 4 + r;
        int e = eh * 96 + we * 48 + j * 16 + lr;
        base[(size_t)d * 192 + e] = acc[i][j][r];
      }
}

// ---------------- softmax rows: reduce 16 partial slices + temp + l2 fold ---
__global__ __launch_bounds__(256) void softmax_k(const float* __restrict__ Sp,
                                                 const float* __restrict__ norm2,
                                                 const float* __restrict__ temp,
                                                 ushort* __restrict__ attn){
  const int wid  = blockIdx.x * 4 + (threadIdx.x >> 6);  // row id [0,3072)
  const int lane = threadIdx.x & 63;
  const int bh = wid / 192, d = wid % 192;
  const int b = bh >> 2, h = bh & 3;
  const float nq = sqrtf(norm2[b*1536 + h*192 + d]);
  const float sc = temp[h] / fmaxf(nq, 1e-12f);
  const float* Sr = Sp + ((size_t)bh * 192 + d) * 192;
  float l[3];
  #pragma unroll
  for (int u = 0; u < 3; ++u){
    int e = lane + u * 64;
    float s = 0.f;
    #pragma unroll
    for (int kc = 0; kc < 16; ++kc)
      s += Sr[(size_t)kc * (16*192*192) + e];
    float nk = sqrtf(norm2[b*1536 + 768 + h*192 + e]);
    l[u] = s * sc / fmaxf(nk, 1e-12f);
  }
  float m = fmaxf(l[0], fmaxf(l[1], l[2]));
  #pragma unroll
  for (int off = 32; off; off >>= 1) m = fmaxf(m, __shfl_xor(m, off));
  float p[3], s = 0.f;
  #pragma unroll
  for (int u = 0; u < 3; ++u){ p[u] = expf(l[u] - m); s += p[u]; }
  #pragma unroll
  for (int off = 32; off; off >>= 1) s += __shfl_xor(s, off);
  float inv = 1.f / s;
  ushort* ar = attn + ((size_t)bh * 192 + d) * 192;
  #pragma unroll
  for (int u = 0; u < 3; ++u) ar[lane + u*64] = f2bf(p[u] * inv);
}

// ---------------- out[n][h*192+d] = sum_e V[n][e] * attn[d][e] --------------
__global__ __launch_bounds__(256) void out_gemm(const ushort* __restrict__ Q,
                                                const ushort* __restrict__ attn,
                                                float* __restrict__ out){
  const int bh = blockIdx.y;
  const int b = bh >> 2, h = bh & 3;
  const int n0 = blockIdx.x * 128;
  const int t = threadIdx.x, w = t >> 6, lane = t & 63;
  const int wn = w & 1, wd = w >> 1;
  const int lr = lane & 15, lg = lane >> 4;
  f32x4 acc[4][6];
  #pragma unroll
  for (int i = 0; i < 4; ++i)
    #pragma unroll
    for (int j = 0; j < 6; ++j)
      acc[i][j] = (f32x4){0.f, 0.f, 0.f, 0.f};

  const ushort* Vbase = Q + 1536 + h * 192;
  const ushort* Abase = attn + (size_t)bh * 192 * 192;

  #pragma unroll
  for (int kk = 0; kk < 6; ++kk){
    const int e = kk * 32 + lg * 8;
    short8_t av[4], bv[6];
    #pragma unroll
    for (int f = 0; f < 4; ++f){
      int n = n0 + wn*64 + f*16 + lr;
      av[f] = *(const short8_t*)(Vbase + (size_t)(b*N_ + n) * CQ_ + e);
    }
    #pragma unroll
    for (int f = 0; f < 6; ++f){
      int d = wd*96 + f*16 + lr;
      bv[f] = *(const short8_t*)(Abase + d * 192 + e);
    }
    #pragma unroll
    for (int i = 0; i < 4; ++i)
      #pragma unroll
      for (int j = 0; j < 6; ++j)
        acc[i][j] = __builtin_amdgcn_mfma_f32_16x16x32_bf16(av[i], bv[j], acc[i][j], 0, 0, 0);
  }
  #pragma unroll
  for (int i = 0; i < 4; ++i)
    #pragma unroll
    for (int j = 0; j < 6; ++j)
      #pragma unroll
      for (int r = 0; r < 4; ++r){
        int n = n0 + wn*64 + i*16 + lg*4 + r;
        int c = h*192 + wd*96 + j*16 + lr;
        out[(size_t)(b*N_ + n) * 768 + c] = acc[i][j][r];
      }
}

// ---------------------------------------------------------------------------
extern "C" void kernel_launch(void* const* d_in, const int* in_sizes, int n_in,
                              void* d_out, int out_size, void* d_ws, size_t ws_size,
                              hipStream_t stream){
  const float* x    = (const float*)d_in[0];
  const float* Wq   = (const float*)d_in[1];
  const float* temp = (const float*)d_in[2];
  float* out = (float*)d_out;
  char* ws = (char*)d_ws;

  // workspace layout (bytes) — S_part/attn overlay xb (dead after gemm_qkvv)
  ushort* xb    = (ushort*)(ws + 0);          //  50,331,648 (dead after gemm)
  float*  S_part= (float*)(ws + 0);           //  37,748,736 (16 slices)
  ushort* attn  = (ushort*)(ws + 37748736);   //   1,179,648
  ushort* Wb    = (ushort*)(ws + 50331648);   //   3,538,944
  ushort* qkvv  = (ushort*)(ws + 53870592);   // 150,994,944
  float*  norm2 = (float*)(ws + 204865536);   //      24,576

  hipMemsetAsync(norm2, 0, 24576, stream);

  cvt_bf16<<<6291456/256, 256, 0, stream>>>(x,  xb, 6291456);
  cvt_bf16<<<442368/256,  256, 0, stream>>>(Wq, Wb, 442368);

  gemm_qkvv<<<dim3(18, 256), 256, 0, stream>>>(xb, Wb, qkvv, norm2);

  gram_mfma<<<dim3(16, 16, 2), 256, 0, stream>>>(qkvv, S_part);
  softmax_k<<<768, 256, 0, stream>>>(S_part, norm2, temp, attn);
  out_gemm<<<dim3(64, 16), 256, 0, stream>>>(qkvv, attn, out);
}

// Round 4
// 239.987 us; speedup vs baseline: 4.9080x; 1.1972x over previous
//
#include <hip/hip_runtime.h>
#include <hip/hip_bf16.h>
#include <cstddef>
#include <cstdint>

#define B_   4
#define N_   8192
#define C_   768
#define H_   4
#define D_   192
#define CQ_  2304   // 3*C
#define M_   32768  // B*N

typedef __attribute__((ext_vector_type(8))) short short8_t;
typedef __attribute__((ext_vector_type(4))) float f32x4;

typedef const __attribute__((address_space(1))) uint gq_uint;
typedef __attribute__((address_space(3))) uint lds_uint;

__device__ inline ushort f2bf(float f){
  uint u = __float_as_uint(f);
  u += 0x7FFFu + ((u >> 16) & 1u);   // RNE; inputs are finite
  return (ushort)(u >> 16);
}
__device__ inline float bf2f(ushort u){ return __uint_as_float(((uint)u) << 16); }

// ---------------- fp32 -> bf16 conversion (vectorized) ----------------
__global__ __launch_bounds__(256) void cvt_bf16(const float* __restrict__ src,
                                                ushort* __restrict__ dst, int n4){
  int i = blockIdx.x * 256 + threadIdx.x;
  if (i < n4){
    float4 v = ((const float4*)src)[i];
    ushort4 o;
    o.x = f2bf(v.x); o.y = f2bf(v.y); o.z = f2bf(v.z); o.w = f2bf(v.w);
    ((ushort4*)dst)[i] = o;
  }
}

// ---------------- QKV projection: [32768,768] x [2304,768]^T -> bf16 [32768,2304]
// 256x256 tile, BK=64, 8 waves (2Mx4N), counted-vmcnt double buffer, swizzled LDS.
// Fused: column sum-of-squares for q,k (bx < 6) from fp32 accumulators.
__global__ __launch_bounds__(512, 2) void gemm_qkvv(const ushort* __restrict__ A,
                                                    const ushort* __restrict__ W,
                                                    ushort* __restrict__ Cq,
                                                    float* __restrict__ norm2){
  extern __shared__ ushort lds[];   // 2 buf x (A 16384 + B 16384) ushorts = 128 KiB
  const int t = threadIdx.x;
  // XCD-aware swizzle: 1152 = 8 * 144
  const int bid = blockIdx.x;
  const int wg  = (bid & 7) * 144 + (bid >> 3);
  const int by = wg / 9, bx = wg % 9;
  const int m0 = by * 256, n0 = bx * 256;
  const int wid = t >> 6, lane = t & 63;
  const int wm = wid >> 2, wn = wid & 3;        // wave tile: 128(M) x 64(N)
  const int lr = lane & 15, lg = lane >> 4;
  // staging lane geometry: 8 rows/wave/inst, slot pre-swizzled (involution)
  const int srow  = lane >> 3;
  const int sslot = (lane & 7) ^ srow;

  f32x4 acc[8][4];
  #pragma unroll
  for (int i = 0; i < 8; ++i)
    #pragma unroll
    for (int j = 0; j < 4; ++j)
      acc[i][j] = (f32x4){0.f, 0.f, 0.f, 0.f};

  #define STAGE(KT, CUR)                                                          \
    do {                                                                          \
      const int k0_ = (KT) * 64;                                                  \
      ushort* bA_ = lds + (CUR) * 32768;                                          \
      ushort* bB_ = bA_ + 16384;                                                  \
      _Pragma("unroll")                                                           \
      for (int i_ = 0; i_ < 4; ++i_){                                             \
        const int r_ = i_ * 64 + wid * 8;                                         \
        __builtin_amdgcn_global_load_lds(                                         \
            (gq_uint*)(const void*)(A + (size_t)(m0 + r_ + srow) * 768 + k0_ + sslot * 8), \
            (lds_uint*)(void*)(bA_ + r_ * 64), 16, 0, 0);                         \
        __builtin_amdgcn_global_load_lds(                                         \
            (gq_uint*)(const void*)(W + (size_t)(n0 + r_ + srow) * 768 + k0_ + sslot * 8), \
            (lds_uint*)(void*)(bB_ + r_ * 64), 16, 0, 0);                         \
      }                                                                           \
    } while (0)

  // prologue: T0 -> buf0, T1 -> buf1; wait T0 (keep T1's 8 in flight)
  STAGE(0, 0);
  STAGE(1, 1);
  asm volatile("s_waitcnt vmcnt(8)" ::: "memory");
  __builtin_amdgcn_s_barrier();
  __builtin_amdgcn_sched_barrier(0);

  for (int kt = 0; kt < 12; ++kt){
    const int cur = kt & 1;
    const ushort* bA = lds + cur * 32768;
    const ushort* bB = bA + 16384;

    short8_t af[2][8], bf[2][4];
    #pragma unroll
    for (int kk = 0; kk < 2; ++kk){
      const int sl = ((kk * 4 + lg) ^ (lr & 7)) * 8;
      #pragma unroll
      for (int fm = 0; fm < 8; ++fm)
        af[kk][fm] = *(const short8_t*)(bA + (wm * 128 + fm * 16 + lr) * 64 + sl);
      #pragma unroll
      for (int fn = 0; fn < 4; ++fn)
        bf[kk][fn] = *(const short8_t*)(bB + (wn * 64 + fn * 16 + lr) * 64 + sl);
    }

    // MFMA kk=0 (kk=1 read latency hides underneath)
    __builtin_amdgcn_s_setprio(1);
    #pragma unroll
    for (int fm = 0; fm < 8; ++fm)
      #pragma unroll
      for (int fn = 0; fn < 4; ++fn)
        acc[fm][fn] = __builtin_amdgcn_mfma_f32_16x16x32_bf16(af[0][fm], bf[0][fn], acc[fm][fn], 0, 0, 0);
    __builtin_amdgcn_s_setprio(0);

    // all reads of buf[cur] complete -> safe to overwrite after barrier
    asm volatile("s_waitcnt lgkmcnt(0)" ::: "memory");
    __builtin_amdgcn_sched_barrier(0);
    __builtin_amdgcn_s_barrier();
    __builtin_amdgcn_sched_barrier(0);

    if (kt + 2 < 12) STAGE(kt + 2, cur);

    // MFMA kk=1 (stage issue overlaps)
    __builtin_amdgcn_s_setprio(1);
    #pragma unroll
    for (int fm = 0; fm < 8; ++fm)
      #pragma unroll
      for (int fn = 0; fn < 4; ++fn)
        acc[fm][fn] = __builtin_amdgcn_mfma_f32_16x16x32_bf16(af[1][fm], bf[1][fn], acc[fm][fn], 0, 0, 0);
    __builtin_amdgcn_s_setprio(0);

    if (kt < 11){
      if (kt + 2 < 12) asm volatile("s_waitcnt vmcnt(8)" ::: "memory");  // T(kt+1) landed
      else             asm volatile("s_waitcnt vmcnt(0)" ::: "memory");  // tail drain
      __builtin_amdgcn_s_barrier();
      __builtin_amdgcn_sched_barrier(0);
    }
  }
  #undef STAGE

  // epilogue: C write (bf16)
  #pragma unroll
  for (int fm = 0; fm < 8; ++fm)
    #pragma unroll
    for (int fn = 0; fn < 4; ++fn)
      #pragma unroll
      for (int r = 0; r < 4; ++r){
        int m = m0 + wm * 128 + fm * 16 + lg * 4 + r;
        int c = n0 + wn * 64 + fn * 16 + lr;
        Cq[(size_t)m * CQ_ + c] = f2bf(acc[fm][fn][r]);
      }

  // fused column sum-of-squares for q,k columns (n0 < 1536)
  if (bx < 6){
    const int b = m0 >> 13;
    #pragma unroll
    for (int fn = 0; fn < 4; ++fn){
      float s = 0.f;
      #pragma unroll
      for (int fm = 0; fm < 8; ++fm)
        #pragma unroll
        for (int r = 0; r < 4; ++r)
          s = fmaf(acc[fm][fn][r], acc[fm][fn][r], s);
      s += __shfl_xor(s, 16);
      s += __shfl_xor(s, 32);
      if (lg == 0)
        atomicAdd(&norm2[b * 1536 + n0 + wn * 64 + fn * 16 + lr], s);
    }
  }
}

// ---------------- Gram via MFMA: S_part[kc][bh][d][e] partial sums ----------
__global__ __launch_bounds__(256) void gram_mfma(const ushort* __restrict__ Qk,
                                                 float* __restrict__ Sp){
  const int kc = blockIdx.x;      // 16 K-chunks of 512 rows
  const int bh = blockIdx.y;      // 16
  const int eh = blockIdx.z;      // 2 e-halves of 96
  const int b = bh >> 2, h = bh & 3;
  __shared__ __align__(16) ushort qs[32][194];
  __shared__ __align__(16) ushort ks[32][98];
  const int t = threadIdx.x;
  const int w = t >> 6, lane = t & 63;
  const int wd = w >> 1, we = w & 1;
  const int lr = lane & 15, lg = lane >> 4;

  f32x4 acc[6][3];
  #pragma unroll
  for (int i = 0; i < 6; ++i)
    #pragma unroll
    for (int j = 0; j < 3; ++j)
      acc[i][j] = (f32x4){0.f, 0.f, 0.f, 0.f};

  const uint* qb = (const uint*)Qk + ((size_t)b * N_ * CQ_ + h * 192) / 2;
  const uint* kb = (const uint*)Qk + ((size_t)b * N_ * CQ_ + 768 + h * 192 + eh * 96) / 2;

  for (int it = 0; it < 16; ++it){
    const int n0 = kc * 512 + it * 32;
    __syncthreads();
    #pragma unroll
    for (int u = 0; u < 3; ++u){
      int g = u * 256 + t;
      int row = g / 24, c4 = g % 24;
      uint4 v = ((const uint4*)(qb + (size_t)(n0 + row) * 1152))[c4];
      uint* dst = (uint*)&qs[row][8 * c4];
      dst[0] = v.x; dst[1] = v.y; dst[2] = v.z; dst[3] = v.w;
    }
    #pragma unroll
    for (int u = 0; u < 3; ++u){
      int g = u * 256 + t;
      int row = g / 24, c2 = g % 24;
      uint2 v = ((const uint2*)(kb + (size_t)(n0 + row) * 1152))[c2];
      uint* dst = (uint*)&ks[row][4 * c2];
      dst[0] = v.x; dst[1] = v.y;
    }
    __syncthreads();
    union { uint u[4]; short8_t v; } af[6], bf[3];
    #pragma unroll
    for (int i = 0; i < 6; ++i){
      int d = wd * 96 + i * 16 + lr;
      #pragma unroll
      for (int p = 0; p < 4; ++p)
        af[i].u[p] = (uint)qs[lg*8 + 2*p][d] | ((uint)qs[lg*8 + 2*p + 1][d] << 16);
    }
    #pragma unroll
    for (int j = 0; j < 3; ++j){
      int e = we * 48 + j * 16 + lr;
      #pragma unroll
      for (int p = 0; p < 4; ++p)
        bf[j].u[p] = (uint)ks[lg*8 + 2*p][e] | ((uint)ks[lg*8 + 2*p + 1][e] << 16);
    }
    #pragma unroll
    for (int i = 0; i < 6; ++i)
      #pragma unroll
      for (int j = 0; j < 3; ++j)
        acc[i][j] = __builtin_amdgcn_mfma_f32_16x16x32_bf16(af[i].v, bf[j].v, acc[i][j], 0, 0, 0);
  }
  float* base = Sp + (size_t)(kc * 16 + bh) * 192 * 192;
  #pragma unroll
  for (int i = 0; i < 6; ++i)
    #pragma unroll
    for (int j = 0; j < 3; ++j)
      #pragma unroll
      for (int r = 0; r < 4; ++r){
        int d = wd * 96 + i * 16 + lg * 4 + r;
        int e = eh * 96 + we * 48 + j * 16 + lr;
        base[(size_t)d * 192 + e] = acc[i][j][r];
      }
}

// ---------------- softmax rows: reduce 16 partial slices + temp + l2 fold ---
__global__ __launch_bounds__(256) void softmax_k(const float* __restrict__ Sp,
                                                 const float* __restrict__ norm2,
                                                 const float* __restrict__ temp,
                                                 ushort* __restrict__ attn){
  const int wid  = blockIdx.x * 4 + (threadIdx.x >> 6);  // row id [0,3072)
  const int lane = threadIdx.x & 63;
  const int bh = wid / 192, d = wid % 192;
  const int b = bh >> 2, h = bh & 3;
  const float nq = sqrtf(norm2[b*1536 + h*192 + d]);
  const float sc = temp[h] / fmaxf(nq, 1e-12f);
  const float* Sr = Sp + ((size_t)bh * 192 + d) * 192;
  float l[3];
  #pragma unroll
  for (int u = 0; u < 3; ++u){
    int e = lane + u * 64;
    float s = 0.f;
    #pragma unroll
    for (int kc = 0; kc < 16; ++kc)
      s += Sr[(size_t)kc * (16*192*192) + e];
    float nk = sqrtf(norm2[b*1536 + 768 + h*192 + e]);
    l[u] = s * sc / fmaxf(nk, 1e-12f);
  }
  float m = fmaxf(l[0], fmaxf(l[1], l[2]));
  #pragma unroll
  for (int off = 32; off; off >>= 1) m = fmaxf(m, __shfl_xor(m, off));
  float p[3], s = 0.f;
  #pragma unroll
  for (int u = 0; u < 3; ++u){ p[u] = expf(l[u] - m); s += p[u]; }
  #pragma unroll
  for (int off = 32; off; off >>= 1) s += __shfl_xor(s, off);
  float inv = 1.f / s;
  ushort* ar = attn + ((size_t)bh * 192 + d) * 192;
  #pragma unroll
  for (int u = 0; u < 3; ++u) ar[lane + u*64] = f2bf(p[u] * inv);
}

// ---------------- out[n][h*192+d] = sum_e V[n][e] * attn[d][e] --------------
__global__ __launch_bounds__(256) void out_gemm(const ushort* __restrict__ Q,
                                                const ushort* __restrict__ attn,
                                                float* __restrict__ out){
  const int bh = blockIdx.y;
  const int b = bh >> 2, h = bh & 3;
  const int n0 = blockIdx.x * 128;
  const int t = threadIdx.x, w = t >> 6, lane = t & 63;
  const int wn = w & 1, wd = w >> 1;
  const int lr = lane & 15, lg = lane >> 4;
  f32x4 acc[4][6];
  #pragma unroll
  for (int i = 0; i < 4; ++i)
    #pragma unroll
    for (int j = 0; j < 6; ++j)
      acc[i][j] = (f32x4){0.f, 0.f, 0.f, 0.f};

  const ushort* Vbase = Q + 1536 + h * 192;
  const ushort* Abase = attn + (size_t)bh * 192 * 192;

  #pragma unroll
  for (int kk = 0; kk < 6; ++kk){
    const int e = kk * 32 + lg * 8;
    short8_t av[4], bv[6];
    #pragma unroll
    for (int f = 0; f < 4; ++f){
      int n = n0 + wn*64 + f*16 + lr;
      av[f] = *(const short8_t*)(Vbase + (size_t)(b*N_ + n) * CQ_ + e);
    }
    #pragma unroll
    for (int f = 0; f < 6; ++f){
      int d = wd*96 + f*16 + lr;
      bv[f] = *(const short8_t*)(Abase + d * 192 + e);
    }
    #pragma unroll
    for (int i = 0; i < 4; ++i)
      #pragma unroll
      for (int j = 0; j < 6; ++j)
        acc[i][j] = __builtin_amdgcn_mfma_f32_16x16x32_bf16(av[i], bv[j], acc[i][j], 0, 0, 0);
  }
  #pragma unroll
  for (int i = 0; i < 4; ++i)
    #pragma unroll
    for (int j = 0; j < 6; ++j)
      #pragma unroll
      for (int r = 0; r < 4; ++r){
        int n = n0 + wn*64 + i*16 + lg*4 + r;
        int c = h*192 + wd*96 + j*16 + lr;
        out[(size_t)(b*N_ + n) * 768 + c] = acc[i][j][r];
      }
}

// ---------------------------------------------------------------------------
extern "C" void kernel_launch(void* const* d_in, const int* in_sizes, int n_in,
                              void* d_out, int out_size, void* d_ws, size_t ws_size,
                              hipStream_t stream){
  const float* x    = (const float*)d_in[0];
  const float* Wq   = (const float*)d_in[1];
  const float* temp = (const float*)d_in[2];
  float* out = (float*)d_out;
  char* ws = (char*)d_ws;

  // workspace layout (bytes) — S_part/attn overlay xb (dead after gemm_qkvv)
  ushort* xb    = (ushort*)(ws + 0);          //  50,331,648 (dead after gemm)
  float*  S_part= (float*)(ws + 0);           //  37,748,736 (16 slices)
  ushort* attn  = (ushort*)(ws + 37748736);   //   1,179,648
  ushort* Wb    = (ushort*)(ws + 50331648);   //   3,538,944
  ushort* qkvv  = (ushort*)(ws + 53870592);   // 150,994,944
  float*  norm2 = (float*)(ws + 204865536);   //      24,576

  static_assert(sizeof(ushort) == 2, "");
  hipFuncSetAttribute((const void*)gemm_qkvv,
                      hipFuncAttributeMaxDynamicSharedMemorySize, 131072);

  hipMemsetAsync(norm2, 0, 24576, stream);

  cvt_bf16<<<6291456/256, 256, 0, stream>>>(x,  xb, 6291456);
  cvt_bf16<<<442368/256,  256, 0, stream>>>(Wq, Wb, 442368);

  gemm_qkvv<<<1152, 512, 131072, stream>>>(xb, Wb, qkvv, norm2);

  gram_mfma<<<dim3(16, 16, 2), 256, 0, stream>>>(qkvv, S_part);
  softmax_k<<<768, 256, 0, stream>>>(S_part, norm2, temp, attn);
  out_gemm<<<dim3(64, 16), 256, 0, stream>>>(qkvv, attn, out);
}